// Round 6
// baseline (139.580 us; speedup 1.0000x reference)
//
#include <hip/hip_runtime.h>

typedef __attribute__((ext_vector_type(8))) short s16x8;
typedef __attribute__((ext_vector_type(4))) float f32x4;
typedef __attribute__((ext_vector_type(16))) float f32x16;
typedef __attribute__((ext_vector_type(2))) unsigned u32x2;
typedef __attribute__((ext_vector_type(4))) unsigned u32x4;

#define MFMA32(a, b, c) __builtin_amdgcn_mfma_f32_16x16x32_bf16((a), (b), (c), 0, 0, 0)

#if __has_builtin(__builtin_amdgcn_mfma_f32_32x32x16_bf16)
#define MFMA3216(a, b, c) __builtin_amdgcn_mfma_f32_32x32x16_bf16((a), (b), (c), 0, 0, 0)
#else
#define MFMA3216(a, b, c) (c) /* host-pass parse stub */
#endif

#if __has_builtin(__builtin_amdgcn_exp2f)
#define EXP2F(x) __builtin_amdgcn_exp2f(x)
#else
#define EXP2F(x) __exp2f(x)
#endif

#if __has_builtin(__builtin_amdgcn_rcpf)
#define RCPF(x) __builtin_amdgcn_rcpf(x)
#else
#define RCPF(x) (1.0f / (x))
#endif

#define SL2E 0.25507313f  // (1/sqrt(32)) * log2(e)

__device__ __forceinline__ unsigned pkrne(float a, float b) {
  unsigned ua = __builtin_bit_cast(unsigned, a);
  unsigned ub = __builtin_bit_cast(unsigned, b);
  ua += 0x7FFFu + ((ua >> 16) & 1u);
  ub += 0x7FFFu + ((ub >> 16) & 1u);
  return __builtin_amdgcn_perm(ub, ua, 0x07060302u);
}

// pack two f32 -> bf16 pair by TRUNCATION (1 v_perm); bias cancels in O/l
// because l is accumulated (ones-B MFMA) from the SAME truncated bf16 values.
__device__ __forceinline__ unsigned pktrunc(float a, float b) {
  return __builtin_amdgcn_perm(__builtin_bit_cast(unsigned, b),
                               __builtin_bit_cast(unsigned, a), 0x07060302u);
}

__device__ __forceinline__ unsigned short bfr(float f) {
  unsigned u = __builtin_bit_cast(unsigned, f);
  u += 0x7FFFu + ((u >> 16) & 1u);
  return (unsigned short)(u >> 16);
}

__device__ __forceinline__ float bflo(unsigned u) {
  return __builtin_bit_cast(float, u << 16);
}
__device__ __forceinline__ float bfhi(unsigned u) {
  return __builtin_bit_cast(float, u & 0xFFFF0000u);
}

__device__ __forceinline__ u32x2 plswap(unsigned a, unsigned b) {
#if __has_builtin(__builtin_amdgcn_permlane32_swap)
  return __builtin_amdgcn_permlane32_swap(a, b, false, false);
#else
  unsigned sa = (unsigned)__shfl_xor((int)a, 32, 64);
  unsigned sb = (unsigned)__shfl_xor((int)b, 32, 64);
  bool hi = (threadIdx.x & 63) >= 32;
  u32x2 r;
  r.x = hi ? sb : a;
  r.y = hi ? b : sa;
  return r;
#endif
}

// ---------------------------------------------------------------------------
// Prep: transpose+convert fp32 sources into bf16 k-contiguous layouts.
// ---------------------------------------------------------------------------
__global__ __launch_bounds__(256) void prep_kernel(
    const float* __restrict__ x, const float* __restrict__ wqkv,
    const float* __restrict__ wout, ushort* __restrict__ xbf,
    ushort* __restrict__ wT, ushort* __restrict__ woT) {
  const int t = threadIdx.x;
  const int sub = t & 15, grp = t >> 4;
  const int id = blockIdx.x;
  const float* src;
  ushort* dst;
  int src_ld, k0, n0;
  float sc = 1.f;
  if (id < 512) {
    int mt = id & 63, kt = (id >> 6) & 3, b = id >> 8;
    src = x + (size_t)b * 256 * 4096;
    src_ld = 4096;
    dst = xbf + (size_t)b * 4096 * 256;
    k0 = kt * 64;
    n0 = mt * 64;
  } else if (id < 560) {
    int r = id - 512, nt = r % 12, kt = r / 12;
    src = wqkv;
    src_ld = 768;
    dst = wT;
    k0 = kt * 64;
    n0 = nt * 64;
    if (n0 < 256) sc = SL2E;
  } else {
    int r = id - 560, nt = r & 3, kt = r >> 2;
    src = wout;
    src_ld = 256;
    dst = woT;
    k0 = kt * 64;
    n0 = nt * 64;
  }
  const int k = k0 + grp * 4;
  const int n = n0 + sub * 4;
  unsigned d0[4], d1[4];
#pragma unroll
  for (int i = 0; i < 4; ++i) {
    float4 v = *(const float4*)(src + (size_t)(k + i) * src_ld + n);
    d0[i] = pkrne(v.x * sc, v.y * sc);
    d1[i] = pkrne(v.z * sc, v.w * sc);
  }
  u32x2 r0 = {__builtin_amdgcn_perm(d0[1], d0[0], 0x05040100u),
              __builtin_amdgcn_perm(d0[3], d0[2], 0x05040100u)};
  u32x2 r1 = {__builtin_amdgcn_perm(d0[1], d0[0], 0x07060302u),
              __builtin_amdgcn_perm(d0[3], d0[2], 0x07060302u)};
  u32x2 r2 = {__builtin_amdgcn_perm(d1[1], d1[0], 0x05040100u),
              __builtin_amdgcn_perm(d1[3], d1[2], 0x05040100u)};
  u32x2 r3 = {__builtin_amdgcn_perm(d1[1], d1[0], 0x07060302u),
              __builtin_amdgcn_perm(d1[3], d1[2], 0x07060302u)};
  *(u32x2*)(dst + (size_t)(n + 0) * 256 + k) = r0;
  *(u32x2*)(dst + (size_t)(n + 1) * 256 + k) = r1;
  *(u32x2*)(dst + (size_t)(n + 2) * 256 + k) = r2;
  *(u32x2*)(dst + (size_t)(n + 3) * 256 + k) = r3;
}

// ---------------------------------------------------------------------------
// Fused QKV: D[n][tok] = wT(rows n) x xbf(rows tok).
// Q stored [b,h][tok][dd]. K and V stored FRAGMENT-LINEAR per 64-token tile
// (1KB chunks in the exact order attn's lanes consume them):
//   K: (b*8+h)*131072 + tl*2048 + s*1024 + hK*512 + hi*256 + l5*8 + e
//   V: (b*8+h)*131072 + tl*2048 + s*1024 + hV*512 + hi*256 + d*8 + e
// ---------------------------------------------------------------------------
__global__ __launch_bounds__(256) void qkv_kernel(
    const ushort* __restrict__ xbf, const ushort* __restrict__ wT,
    const float* __restrict__ bq, ushort* __restrict__ QG,
    ushort* __restrict__ KG, ushort* __restrict__ VtG) {
  __shared__ __align__(16) ushort Wl[64][40];
  __shared__ __align__(16) ushort Xl[128][40];
  const int t0 = blockIdx.x * 128;
  const int n0 = blockIdx.y * 64;
  const int t = threadIdx.x;
  const int wid = t >> 6, lane = t & 63;
  const int wy = wid >> 1, wx = wid & 1;
  const int quad = lane >> 4, l16 = lane & 15;
  f32x4 acc[2][4] = {};
  const int wr = t >> 2, wsg = t & 3;
  for (int k0 = 0; k0 < 256; k0 += 32) {
    __syncthreads();
    *(uint4*)&Wl[wr][wsg * 8] =
        *(const uint4*)(wT + (size_t)(n0 + wr) * 256 + k0 + wsg * 8);
#pragma unroll
    for (int i = 0; i < 2; ++i) {
      int fid = t + 256 * i, row = fid >> 2, seg = fid & 3;
      *(uint4*)&Xl[row][seg * 8] =
          *(const uint4*)(xbf + (size_t)(t0 + row) * 256 + k0 + seg * 8);
    }
    __syncthreads();
    s16x8 wf[2], xf[4];
#pragma unroll
    for (int i = 0; i < 2; ++i)
      wf[i] = *(const s16x8*)&Wl[32 * wy + 16 * i + l16][quad * 8];
#pragma unroll
    for (int j = 0; j < 4; ++j)
      xf[j] = *(const s16x8*)&Xl[64 * wx + 16 * j + l16][quad * 8];
#pragma unroll
    for (int i = 0; i < 2; ++i)
#pragma unroll
      for (int j = 0; j < 4; ++j) acc[i][j] = MFMA32(wf[i], xf[j], acc[i][j]);
  }
  if (n0 < 256) {
    // Q: [b,h][tok][dd]
#pragma unroll
    for (int i = 0; i < 2; ++i) {
      int nb = n0 + 32 * wy + 16 * i + 4 * quad;
      float4 b4 = *(const float4*)(bq + nb);
      float bx0 = b4.x * SL2E, bx1 = b4.y * SL2E, bx2 = b4.z * SL2E,
            bx3 = b4.w * SL2E;
      int h = ((nb & 255) >> 5);
      int dd0 = nb & 31;
#pragma unroll
      for (int j = 0; j < 4; ++j) {
        int tok = t0 + 64 * wx + 16 * j + l16;
        int b = tok >> 12, tokn = tok & 4095;
        u32x2 pk = {pkrne(acc[i][j][0] + bx0, acc[i][j][1] + bx1),
                    pkrne(acc[i][j][2] + bx2, acc[i][j][3] + bx3)};
        *(u32x2*)(QG + ((size_t)(b * 8 + h) * 4096 + tokn) * 32 + dd0) = pk;
      }
    }
  } else if (n0 < 512) {
    // K: fragment-linear. dd0 = 16*i + 4*quad -> hK=i, hi=quad>>1,
    // e0=4*(quad&1).
#pragma unroll
    for (int i = 0; i < 2; ++i) {
      int nb = n0 + 32 * wy + 16 * i + 4 * quad;
      float4 b4 = *(const float4*)(bq + nb);
      float bx0 = b4.x, bx1 = b4.y, bx2 = b4.z, bx3 = b4.w;
      int h = ((nb & 255) >> 5);
      size_t fo = (size_t)i * 512 + (quad >> 1) * 256 + (quad & 1) * 4;
#pragma unroll
      for (int j = 0; j < 4; ++j) {
        int tok = t0 + 64 * wx + 16 * j + l16;
        int b = tok >> 12, tokn = tok & 4095;
        int tl = tokn >> 6, ss = (tokn >> 5) & 1, l5 = tokn & 31;
        u32x2 pk = {pkrne(acc[i][j][0] + bx0, acc[i][j][1] + bx1),
                    pkrne(acc[i][j][2] + bx2, acc[i][j][3] + bx3)};
        *(u32x2*)(KG + (size_t)(b * 8 + h) * 131072 + (size_t)tl * 2048 +
                  ss * 1024 + l5 * 8 + fo) = pk;
      }
    }
  } else {
    // V: fragment-linear.
#pragma unroll
    for (int i = 0; i < 2; ++i) {
      int nb = n0 + 32 * wy + 16 * i + 4 * quad;
      float4 b4 = *(const float4*)(bq + nb);
      float bb[4] = {b4.x, b4.y, b4.z, b4.w};
#pragma unroll
      for (int r = 0; r < 4; ++r) {
        int nn = nb + r - 512;
        int h = nn >> 5, d = nn & 31;
#pragma unroll
        for (int j = 0; j < 4; ++j) {
          int tok = t0 + 64 * wx + 16 * j + l16;
          int b = tok >> 12, tokn = tok & 4095;
          int tl = tokn >> 6, ss = (tokn >> 5) & 1;
          int hV = (tokn >> 4) & 1, hii = (tokn >> 3) & 1, e = tokn & 7;
          VtG[(size_t)(b * 8 + h) * 131072 + (size_t)tl * 2048 + ss * 1024 +
              hV * 512 + hii * 256 + d * 8 + e] = bfr(acc[i][j][r] + bb[r]);
        }
      }
    }
  }
}

// ---------------------------------------------------------------------------
// Flash attention, SPLIT-K x3, 32x32 MFMA, BARRIER-FREE register-direct
// with DEPTH-1 REGISTER DOUBLE-BUFFER.
//
// Diagnosis (r2-r5): VALU work ~474 cyc/wave-iter (32 exp2 dominate) is the
// floor; all barrier-coupled schedules lockstep the waves (one wave's stall
// is everyone's), and r3's reg-direct had no prefetch (loads at use, full
// L2 latency exposed). Fix: fragments of tile j+1 load into the OTHER
// register set while tile j computes (~400 cyc cover >= L2 ~200-300); no
// LDS, no barriers; waves drift freely. Split-K x3 -> grid 1536 = 6
// blocks/CU in exactly 2 resident rounds of 3 (launch_bounds(256,3), 170-reg
// budget fits the ~150-reg live set without spill).
// Math order identical to r2/r5 (same MFMA/exp/trunc sequence).
// ---------------------------------------------------------------------------
__device__ __forceinline__ void softpv(const f32x16& S, s16x8 va0, s16x8 va1,
                                       f32x16& o, f32x16& o_l) {
  const s16x8 ones8 = {(short)0x3F80, (short)0x3F80, (short)0x3F80,
                       (short)0x3F80, (short)0x3F80, (short)0x3F80,
                       (short)0x3F80, (short)0x3F80};
  unsigned w8[8];
#pragma unroll
  for (int ii = 0; ii < 8; ++ii)
    w8[ii] = pktrunc(EXP2F(S[2 * ii]), EXP2F(S[2 * ii + 1]));
  u32x2 sw0 = plswap(w8[0], w8[2]);
  u32x2 sw1 = plswap(w8[1], w8[3]);
  u32x2 sw2 = plswap(w8[4], w8[6]);
  u32x2 sw3 = plswap(w8[5], w8[7]);
  u32x4 pa0 = {sw0.x, sw1.x, sw0.y, sw1.y};  // k 0..15 of subtile
  u32x4 pa1 = {sw2.x, sw3.x, sw2.y, sw3.y};  // k 16..31
  const s16x8 pA0 = __builtin_bit_cast(s16x8, pa0);
  const s16x8 pA1 = __builtin_bit_cast(s16x8, pa1);
  o = MFMA3216(pA0, va0, o);
  o = MFMA3216(pA1, va1, o);
  o_l = MFMA3216(pA0, ones8, o_l);
  o_l = MFMA3216(pA1, ones8, o_l);
}

// Load the 4 fragments of one 64-token tile (K or V), base already +lo8.
#define LDT(F0, F1, F2, F3, P)            \
  {                                       \
    F0 = *(const s16x8*)((P));            \
    F1 = *(const s16x8*)((P) + 512);      \
    F2 = *(const s16x8*)((P) + 1024);     \
    F3 = *(const s16x8*)((P) + 1536);     \
  }

// Process one 64-token tile from register fragments.
#define TILE(K0, K1, K2, K3, V0, V1, V2, V3)   \
  {                                            \
    f32x16 S0 = MFMA3216(K0, qf0, fz);         \
    S0 = MFMA3216(K1, qf1, S0);                \
    softpv(S0, V0, V1, o, o_l);                \
    f32x16 S1 = MFMA3216(K2, qf0, fz);         \
    S1 = MFMA3216(K3, qf1, S1);                \
    softpv(S1, V2, V3, o, o_l);                \
  }

__global__ __launch_bounds__(256, 3) void attn_split(
    const ushort* __restrict__ QG, const ushort* __restrict__ KG,
    const ushort* __restrict__ VtG, ushort* __restrict__ OF0,
    ushort* __restrict__ OFb, float* __restrict__ LF) {
  const int id = blockIdx.x;
  const int bh = (id & 7) * 2 + ((id >> 3) & 1);  // XCD-affine heads
  const int q0 = ((id >> 4) & 31) * 128;
  const int sp = id >> 9;                           // split index 0..2
  const int kt0 = (sp * 64 + 2) / 3;                // {0,22,43}
  const int niter = ((sp + 1) * 64 + 2) / 3 - kt0;  // {22,21,21}
  const int t = threadIdx.x;
  const int wid = t >> 6, lane = t & 63;
  const int l5 = lane & 31, hi = lane >> 5;
  const ushort* qp = QG + (size_t)bh * 4096 * 32;
  const int lo8 = lane * 8;
  const ushort* kn = KG + (size_t)bh * 131072 + (size_t)kt0 * 2048 + lo8;
  const ushort* vn = VtG + (size_t)bh * 131072 + (size_t)kt0 * 2048 + lo8;
  const int qw = q0 + 32 * wid;
  // Q fragments (held in regs): B[dk = h*16 + hi*8 + e][q = l5]
  const ushort* qrow = qp + (size_t)(qw + l5) * 32 + hi * 8;
  const s16x8 qf0 = *(const s16x8*)(qrow);
  const s16x8 qf1 = *(const s16x8*)(qrow + 16);
  f32x16 o = {};
  f32x16 o_l = {};
  const f32x16 fz = {};  // loop-invariant zero C operand for QK MFMAs
  s16x8 KA0, KA1, KA2, KA3, VA0, VA1, VA2, VA3;
  s16x8 KB0, KB1, KB2, KB3, VB0, VB1, VB2, VB3;
  // Preload tile kt0 into the A set.
  LDT(KA0, KA1, KA2, KA3, kn)
  LDT(VA0, VA1, VA2, VA3, vn)
  kn += 2048;
  vn += 2048;
  const int pairs = niter >> 1;
  for (int p = 0; p < pairs; ++p) {
    // Prefetch tile 2p+1 into B (always in-range inside the pair loop),
    // then compute tile 2p from A while the B loads fly.
    LDT(KB0, KB1, KB2, KB3, kn)
    LDT(VB0, VB1, VB2, VB3, vn)
    kn += 2048;
    vn += 2048;
    TILE(KA0, KA1, KA2, KA3, VA0, VA1, VA2, VA3)
    if (2 * p + 2 < niter) {
      LDT(KA0, KA1, KA2, KA3, kn)
      LDT(VA0, VA1, VA2, VA3, vn)
      kn += 2048;
      vn += 2048;
    }
    TILE(KB0, KB1, KB2, KB3, VB0, VB1, VB2, VB3)
  }
  if (niter & 1) {
    TILE(KA0, KA1, KA2, KA3, VA0, VA1, VA2, VA3)
  }
  // Store un-normalized bf16 partial O + f32 partial l.
  ushort* OFs = (sp == 0) ? OF0 : OFb + (size_t)(sp - 1) * 2097152;
  float* LFs = LF + (size_t)sp * 65536;
#pragma unroll
  for (int r = 0; r < 16; ++r) {
    int q = qw + (r & 3) + 8 * (r >> 2) + 4 * hi;
    OFs[((size_t)bh * 4096 + q) * 32 + l5] = bfr(o[r]);
  }
  // o_l: C[row=q][col=d], l[q] replicated across d. Lanes l5<16 store row
  // r=l5 of their hi-half.
  float lval = o_l[0];
#pragma unroll
  for (int r = 1; r < 16; ++r) lval = (l5 == r) ? o_l[r] : lval;
  if (l5 < 16)
    LFs[(size_t)bh * 4096 + qw + (l5 & 3) + 8 * (l5 >> 2) + 4 * hi] = lval;
}

// ---------------------------------------------------------------------------
// Out-proj with fused 3-way split-combine + normalization in the staging.
// 64-token tiles -> grid (128,4) = 2 blocks/CU.
// ---------------------------------------------------------------------------
__global__ __launch_bounds__(256) void proj_split(
    const ushort* __restrict__ OF0, const ushort* __restrict__ OFb,
    const float* __restrict__ LF, const ushort* __restrict__ woT,
    const float* __restrict__ bo, float* __restrict__ out) {
  __shared__ __align__(16) ushort Wl[64][40];
  __shared__ __align__(16) ushort Xl[64][40];
  const int t0 = blockIdx.x * 64;
  const int c0 = blockIdx.y * 64;
  const int t = threadIdx.x;
  const int wid = t >> 6, lane = t & 63;
  const int wy = wid >> 1, wx = wid & 1;
  const int quad = lane >> 4, l16 = lane & 15;
  f32x4 acc[2][2] = {};
  const int wr = t >> 2, wsg = t & 3;
  const int c8 = (t & 7) * 4;  // dd column (4 ushorts)
  for (int k0 = 0; k0 < 256; k0 += 32) {
    __syncthreads();
    *(uint4*)&Wl[wr][wsg * 8] =
        *(const uint4*)(woT + (size_t)(c0 + wr) * 256 + k0 + wsg * 8);
    const int hh = k0 >> 5;
#pragma unroll
    for (int p = 0; p < 2; ++p) {
      int row = 32 * p + (t >> 3);
      int tok = t0 + row, bb = tok >> 12, tokn = tok & 4095;
      size_t ro = (size_t)(bb * 8 + hh) * 4096 + tokn;
      size_t oi = ro * 32 + c8;
      uint2 a0 = *(const uint2*)(OF0 + oi);
      uint2 a1 = *(const uint2*)(OFb + oi);
      uint2 a2 = *(const uint2*)(OFb + 2097152 + oi);
      float l = LF[ro] + LF[65536 + ro] + LF[131072 + ro];
      float inv = RCPF(l);
      f32x4 s;
      s[0] = bflo(a0.x) + bflo(a1.x) + bflo(a2.x);
      s[1] = bfhi(a0.x) + bfhi(a1.x) + bfhi(a2.x);
      s[2] = bflo(a0.y) + bflo(a1.y) + bflo(a2.y);
      s[3] = bfhi(a0.y) + bfhi(a1.y) + bfhi(a2.y);
      s *= inv;
      u32x2 pk = {pkrne(s[0], s[1]), pkrne(s[2], s[3])};
      *(u32x2*)&Xl[row][c8] = pk;
    }
    __syncthreads();
    s16x8 wf[2], xf[2];
#pragma unroll
    for (int i = 0; i < 2; ++i)
      wf[i] = *(const s16x8*)&Wl[32 * wy + 16 * i + l16][quad * 8];
#pragma unroll
    for (int j = 0; j < 2; ++j)
      xf[j] = *(const s16x8*)&Xl[32 * wx + 16 * j + l16][quad * 8];
#pragma unroll
    for (int i = 0; i < 2; ++i)
#pragma unroll
      for (int j = 0; j < 2; ++j) acc[i][j] = MFMA32(wf[i], xf[j], acc[i][j]);
  }
#pragma unroll
  for (int i = 0; i < 2; ++i) {
    int cb = c0 + 32 * wy + 16 * i + 4 * quad;
    float4 b4 = *(const float4*)(bo + cb);
    float bb[4] = {b4.x, b4.y, b4.z, b4.w};
#pragma unroll
    for (int j = 0; j < 2; ++j) {
      int tok = t0 + 32 * wx + 16 * j + l16;
      int b = tok >> 12, tokn = tok & 4095;
#pragma unroll
      for (int r = 0; r < 4; ++r)
        out[((size_t)(b * 256 + cb + r)) * 4096 + tokn] = acc[i][j][r] + bb[r];
    }
  }
}

extern "C" void kernel_launch(void* const* d_in, const int* in_sizes, int n_in,
                              void* d_out, int out_size, void* d_ws, size_t ws_size,
                              hipStream_t stream) {
  (void)in_sizes; (void)n_in; (void)out_size; (void)ws_size;
  const float* x = (const float*)d_in[0];
  const float* wq = (const float*)d_in[1];
  const float* bq = (const float*)d_in[2];
  const float* wo = (const float*)d_in[3];
  const float* bo = (const float*)d_in[4];
  float* out = (float*)d_out;
  ushort* ws = (ushort*)d_ws;
  // ws layout:
  ushort* xbf = ws;                    // [8192][256]  (dead after qkv)
  ushort* OF0 = ws;                    // split0 partial O overlays dead xbf
  ushort* QG  = ws + 2097152;          // [2][8][4096][32]
  ushort* KG  = ws + 4194304;          // fragment-linear tiles
  ushort* VtG = ws + 6291456;          // fragment-linear tiles
  ushort* wT  = ws + 8388608;          // [768][256]
  ushort* woT = ws + 8585216;          // [256][256]
  ushort* OFb = ws + 8650752;          // splits 1,2: 2 x 2,097,152 ushorts
  float* LF = (float*)(ws + 12845056); // [3][16][4096] f32
  prep_kernel<<<576, 256, 0, stream>>>(x, wq, wo, xbf, wT, woT);
  qkv_kernel<<<dim3(64, 12), 256, 0, stream>>>(xbf, wT, bq, QG, KG, VtG);
  attn_split<<<1536, 256, 0, stream>>>(QG, KG, VtG, OF0, OFb, LF);
  proj_split<<<dim3(128, 4), 256, 0, stream>>>(OF0, OFb, LF, woT, bo, out);
}

// Round 7
// 134.668 us; speedup vs baseline: 1.0365x; 1.0365x over previous
//
#include <hip/hip_runtime.h>

typedef __attribute__((ext_vector_type(8))) short s16x8;
typedef __attribute__((ext_vector_type(4))) float f32x4;
typedef __attribute__((ext_vector_type(16))) float f32x16;
typedef __attribute__((ext_vector_type(2))) unsigned u32x2;
typedef __attribute__((ext_vector_type(4))) unsigned u32x4;

#define MFMA32(a, b, c) __builtin_amdgcn_mfma_f32_16x16x32_bf16((a), (b), (c), 0, 0, 0)

#if __has_builtin(__builtin_amdgcn_mfma_f32_32x32x16_bf16)
#define MFMA3216(a, b, c) __builtin_amdgcn_mfma_f32_32x32x16_bf16((a), (b), (c), 0, 0, 0)
#else
#define MFMA3216(a, b, c) (c) /* host-pass parse stub */
#endif

#if __has_builtin(__builtin_amdgcn_exp2f)
#define EXP2F(x) __builtin_amdgcn_exp2f(x)
#else
#define EXP2F(x) __exp2f(x)
#endif

#if __has_builtin(__builtin_amdgcn_rcpf)
#define RCPF(x) __builtin_amdgcn_rcpf(x)
#else
#define RCPF(x) (1.0f / (x))
#endif

#define SL2E 0.25507313f  // (1/sqrt(32)) * log2(e)

__device__ __forceinline__ unsigned pkrne(float a, float b) {
  unsigned ua = __builtin_bit_cast(unsigned, a);
  unsigned ub = __builtin_bit_cast(unsigned, b);
  ua += 0x7FFFu + ((ua >> 16) & 1u);
  ub += 0x7FFFu + ((ub >> 16) & 1u);
  return __builtin_amdgcn_perm(ub, ua, 0x07060302u);
}

// pack two f32 -> bf16 pair by TRUNCATION (1 v_perm); bias cancels in O/l
// because l is accumulated (ones-B MFMA) from the SAME truncated bf16 values.
__device__ __forceinline__ unsigned pktrunc(float a, float b) {
  return __builtin_amdgcn_perm(__builtin_bit_cast(unsigned, b),
                               __builtin_bit_cast(unsigned, a), 0x07060302u);
}

__device__ __forceinline__ unsigned short bfr(float f) {
  unsigned u = __builtin_bit_cast(unsigned, f);
  u += 0x7FFFu + ((u >> 16) & 1u);
  return (unsigned short)(u >> 16);
}

__device__ __forceinline__ float bflo(unsigned u) {
  return __builtin_bit_cast(float, u << 16);
}
__device__ __forceinline__ float bfhi(unsigned u) {
  return __builtin_bit_cast(float, u & 0xFFFF0000u);
}

__device__ __forceinline__ u32x2 plswap(unsigned a, unsigned b) {
#if __has_builtin(__builtin_amdgcn_permlane32_swap)
  return __builtin_amdgcn_permlane32_swap(a, b, false, false);
#else
  unsigned sa = (unsigned)__shfl_xor((int)a, 32, 64);
  unsigned sb = (unsigned)__shfl_xor((int)b, 32, 64);
  bool hi = (threadIdx.x & 63) >= 32;
  u32x2 r;
  r.x = hi ? sb : a;
  r.y = hi ? b : sa;
  return r;
#endif
}

// Async global->LDS: per-lane 16B from g (per-lane addr) lands at
// lds_base + lane*16 (wave-uniform base, lane-linear order).
__device__ __forceinline__ void stage16(const ushort* g, ushort* l, int lane) {
#if __has_builtin(__builtin_amdgcn_global_load_lds)
  __builtin_amdgcn_global_load_lds(
      (__attribute__((address_space(1))) unsigned int*)(unsigned long long)(
          const void*)g,
      (__attribute__((address_space(3))) unsigned int*)(unsigned)(
          unsigned long long)(const void*)l,
      16, 0, 0);
#else
  *(uint4*)(l + lane * 8) = *(const uint4*)g;
#endif
}

// Fragment-linear address helpers (ushort index of a (n,k) element).
// X (tok-tiles of 128): tile 32768, kstep 4096, chunk((n>>4)&7) 512,
//   quad((k>>3)&3) 128, l16(n&15) 8, e(k&7).
__device__ __forceinline__ size_t flX(int n, int k) {
  return (size_t)(n >> 7) * 32768 + (size_t)(k >> 5) * 4096 +
         ((n >> 4) & 7) * 512 + ((k >> 3) & 3) * 128 + (n & 15) * 8 + (k & 7);
}
// W / WO (n-tiles of 64): tile 16384, kstep 2048, chunk((n>>4)&3) 512.
__device__ __forceinline__ size_t flW(int n, int k) {
  return (size_t)(n >> 6) * 16384 + (size_t)(k >> 5) * 2048 +
         ((n >> 4) & 3) * 512 + ((k >> 3) & 3) * 128 + (n & 15) * 8 + (k & 7);
}

// ---------------------------------------------------------------------------
// Prep: transpose+convert fp32 sources into bf16 FRAGMENT-LINEAR layouts
// (same math/rounding as before; only the write addresses changed, so qkv
// and proj can stage via global_load_lds with zero address VALU).
// ---------------------------------------------------------------------------
__global__ __launch_bounds__(256) void prep_kernel(
    const float* __restrict__ x, const float* __restrict__ wqkv,
    const float* __restrict__ wout, ushort* __restrict__ xbf,
    ushort* __restrict__ wT, ushort* __restrict__ woT) {
  const int t = threadIdx.x;
  const int sub = t & 15, grp = t >> 4;
  const int id = blockIdx.x;
  const float* src;
  ushort* dst;
  int src_ld, k0, n0;
  bool isX = false;
  float sc = 1.f;
  if (id < 512) {
    int mt = id & 63, kt = (id >> 6) & 3, b = id >> 8;
    src = x + (size_t)b * 256 * 4096;
    src_ld = 4096;
    dst = xbf + (size_t)b * 1048576;
    k0 = kt * 64;
    n0 = mt * 64;
    isX = true;
  } else if (id < 560) {
    int r = id - 512, nt = r % 12, kt = r / 12;
    src = wqkv;
    src_ld = 768;
    dst = wT;
    k0 = kt * 64;
    n0 = nt * 64;
    if (n0 < 256) sc = SL2E;
  } else {
    int r = id - 560, nt = r & 3, kt = r >> 2;
    src = wout;
    src_ld = 256;
    dst = woT;
    k0 = kt * 64;
    n0 = nt * 64;
  }
  const int k = k0 + grp * 4;
  const int n = n0 + sub * 4;
  unsigned d0[4], d1[4];
#pragma unroll
  for (int i = 0; i < 4; ++i) {
    float4 v = *(const float4*)(src + (size_t)(k + i) * src_ld + n);
    d0[i] = pkrne(v.x * sc, v.y * sc);
    d1[i] = pkrne(v.z * sc, v.w * sc);
  }
  // rj = bf16 of rows (n+j) at cols k..k+3 (k-pairs along k).
  u32x2 r0 = {__builtin_amdgcn_perm(d0[1], d0[0], 0x05040100u),
              __builtin_amdgcn_perm(d0[3], d0[2], 0x05040100u)};
  u32x2 r1 = {__builtin_amdgcn_perm(d0[1], d0[0], 0x07060302u),
              __builtin_amdgcn_perm(d0[3], d0[2], 0x07060302u)};
  u32x2 r2 = {__builtin_amdgcn_perm(d1[1], d1[0], 0x05040100u),
              __builtin_amdgcn_perm(d1[3], d1[2], 0x05040100u)};
  u32x2 r3 = {__builtin_amdgcn_perm(d1[1], d1[0], 0x07060302u),
              __builtin_amdgcn_perm(d1[3], d1[2], 0x07060302u)};
  if (isX) {
    *(u32x2*)(dst + flX(n + 0, k)) = r0;
    *(u32x2*)(dst + flX(n + 1, k)) = r1;
    *(u32x2*)(dst + flX(n + 2, k)) = r2;
    *(u32x2*)(dst + flX(n + 3, k)) = r3;
  } else {
    *(u32x2*)(dst + flW(n + 0, k)) = r0;
    *(u32x2*)(dst + flW(n + 1, k)) = r1;
    *(u32x2*)(dst + flW(n + 2, k)) = r2;
    *(u32x2*)(dst + flW(n + 3, k)) = r3;
  }
}

// ---------------------------------------------------------------------------
// Fused QKV: D[n][tok] = wT(rows n) x xbf(rows tok).
// Staging via global_load_lds from fragment-linear wT/xbf into LINEAR LDS
// (zero addr VALU, zero bank conflicts, ONE barrier per 32-k step).
// Q stored [b,h][tok][dd]. K and V stored FRAGMENT-LINEAR per 64-token tile
// (1KB chunks in the exact order attn's lanes consume them):
//   K: (b*8+h)*131072 + tl*2048 + s*1024 + hK*512 + hi*256 + l5*8 + e
//   V: (b*8+h)*131072 + tl*2048 + s*1024 + hV*512 + hi*256 + d*8 + e
// ---------------------------------------------------------------------------
__global__ __launch_bounds__(256) void qkv_kernel(
    const ushort* __restrict__ xbf, const ushort* __restrict__ wT,
    const float* __restrict__ bq, ushort* __restrict__ QG,
    ushort* __restrict__ KG, ushort* __restrict__ VtG) {
  __shared__ __align__(64) ushort WL[2][2048];
  __shared__ __align__(64) ushort XL[2][4096];
  const int t0 = blockIdx.x * 128;
  const int n0 = blockIdx.y * 64;
  const int t = threadIdx.x;
  const int wid = t >> 6, lane = t & 63;
  const int wy = wid >> 1, wx = wid & 1;
  const int quad = lane >> 4, l16 = lane & 15;
  const int lo8 = lane * 8;
  f32x4 acc[2][4] = {};
  // Per-wave staging sources (wave wid: W chunk wid, X chunks 2wid,2wid+1).
  const ushort* wsrc = wT + (size_t)blockIdx.y * 16384 + wid * 512 + lo8;
  const ushort* xsrc = xbf + (size_t)blockIdx.x * 32768 + wid * 1024 + lo8;
  stage16(wsrc, &WL[0][wid * 512], lane);
  stage16(xsrc, &XL[0][wid * 1024], lane);
  stage16(xsrc + 512, &XL[0][wid * 1024 + 512], lane);
  __syncthreads();
#pragma unroll
  for (int ks = 0; ks < 8; ++ks) {
    const int cur = ks & 1;
    if (ks + 1 < 8) {
      stage16(wsrc + (ks + 1) * 2048, &WL[cur ^ 1][wid * 512], lane);
      stage16(xsrc + (size_t)(ks + 1) * 4096, &XL[cur ^ 1][wid * 1024], lane);
      stage16(xsrc + (size_t)(ks + 1) * 4096 + 512,
              &XL[cur ^ 1][wid * 1024 + 512], lane);
    }
    s16x8 wf[2], xf[4];
#pragma unroll
    for (int i = 0; i < 2; ++i)
      wf[i] = *(const s16x8*)&WL[cur][(2 * wy + i) * 512 + lo8];
#pragma unroll
    for (int j = 0; j < 4; ++j)
      xf[j] = *(const s16x8*)&XL[cur][(4 * wx + j) * 512 + lo8];
#pragma unroll
    for (int i = 0; i < 2; ++i)
#pragma unroll
      for (int j = 0; j < 4; ++j) acc[i][j] = MFMA32(wf[i], xf[j], acc[i][j]);
    __syncthreads();
  }
  if (n0 < 256) {
    // Q: [b,h][tok][dd]
#pragma unroll
    for (int i = 0; i < 2; ++i) {
      int nb = n0 + 32 * wy + 16 * i + 4 * quad;
      float4 b4 = *(const float4*)(bq + nb);
      float bx0 = b4.x * SL2E, bx1 = b4.y * SL2E, bx2 = b4.z * SL2E,
            bx3 = b4.w * SL2E;
      int h = ((nb & 255) >> 5);
      int dd0 = nb & 31;
#pragma unroll
      for (int j = 0; j < 4; ++j) {
        int tok = t0 + 64 * wx + 16 * j + l16;
        int b = tok >> 12, tokn = tok & 4095;
        u32x2 pk = {pkrne(acc[i][j][0] + bx0, acc[i][j][1] + bx1),
                    pkrne(acc[i][j][2] + bx2, acc[i][j][3] + bx3)};
        *(u32x2*)(QG + ((size_t)(b * 8 + h) * 4096 + tokn) * 32 + dd0) = pk;
      }
    }
  } else if (n0 < 512) {
    // K: fragment-linear. dd0 = 16*i + 4*quad -> hK=i, hi=quad>>1,
    // e0=4*(quad&1).
#pragma unroll
    for (int i = 0; i < 2; ++i) {
      int nb = n0 + 32 * wy + 16 * i + 4 * quad;
      float4 b4 = *(const float4*)(bq + nb);
      float bx0 = b4.x, bx1 = b4.y, bx2 = b4.z, bx3 = b4.w;
      int h = ((nb & 255) >> 5);
      size_t fo = (size_t)i * 512 + (quad >> 1) * 256 + (quad & 1) * 4;
#pragma unroll
      for (int j = 0; j < 4; ++j) {
        int tok = t0 + 64 * wx + 16 * j + l16;
        int b = tok >> 12, tokn = tok & 4095;
        int tl = tokn >> 6, ss = (tokn >> 5) & 1, l5 = tokn & 31;
        u32x2 pk = {pkrne(acc[i][j][0] + bx0, acc[i][j][1] + bx1),
                    pkrne(acc[i][j][2] + bx2, acc[i][j][3] + bx3)};
        *(u32x2*)(KG + (size_t)(b * 8 + h) * 131072 + (size_t)tl * 2048 +
                  ss * 1024 + l5 * 8 + fo) = pk;
      }
    }
  } else {
    // V: fragment-linear.
#pragma unroll
    for (int i = 0; i < 2; ++i) {
      int nb = n0 + 32 * wy + 16 * i + 4 * quad;
      float4 b4 = *(const float4*)(bq + nb);
      float bb[4] = {b4.x, b4.y, b4.z, b4.w};
#pragma unroll
      for (int r = 0; r < 4; ++r) {
        int nn = nb + r - 512;
        int h = nn >> 5, d = nn & 31;
#pragma unroll
        for (int j = 0; j < 4; ++j) {
          int tok = t0 + 64 * wx + 16 * j + l16;
          int b = tok >> 12, tokn = tok & 4095;
          int tl = tokn >> 6, ss = (tokn >> 5) & 1;
          int hV = (tokn >> 4) & 1, hii = (tokn >> 3) & 1, e = tokn & 7;
          VtG[(size_t)(b * 8 + h) * 131072 + (size_t)tl * 2048 + ss * 1024 +
              hV * 512 + hii * 256 + d * 8 + e] = bfr(acc[i][j][r] + bb[r]);
        }
      }
    }
  }
}

// ---------------------------------------------------------------------------
// Flash attention, SPLIT-K x2, 32x32 MFMA. The proven r2 lockstep schedule
// (best measured: 49.8us) with global_load_lds staging from the
// fragment-linear K/V layouts into LINEAR double-buffered LDS: stage tile
// j+1 asynchronously at the top of iter j, compute tile j, one
// __syncthreads (its vmcnt drain IS the prefetch-complete wait, covered by
// the whole iter body). 4 waves share each 8KB tile via LDS (4x less L1/L2
// traffic than r3/r6's register-direct path, which measured L1-line-bound).
// ---------------------------------------------------------------------------
__device__ __forceinline__ void softpv(const f32x16& S, s16x8 va0, s16x8 va1,
                                       f32x16& o, f32x16& o_l) {
  const s16x8 ones8 = {(short)0x3F80, (short)0x3F80, (short)0x3F80,
                       (short)0x3F80, (short)0x3F80, (short)0x3F80,
                       (short)0x3F80, (short)0x3F80};
  unsigned w8[8];
#pragma unroll
  for (int ii = 0; ii < 8; ++ii)
    w8[ii] = pktrunc(EXP2F(S[2 * ii]), EXP2F(S[2 * ii + 1]));
  u32x2 sw0 = plswap(w8[0], w8[2]);
  u32x2 sw1 = plswap(w8[1], w8[3]);
  u32x2 sw2 = plswap(w8[4], w8[6]);
  u32x2 sw3 = plswap(w8[5], w8[7]);
  u32x4 pa0 = {sw0.x, sw1.x, sw0.y, sw1.y};  // k 0..15 of subtile
  u32x4 pa1 = {sw2.x, sw3.x, sw2.y, sw3.y};  // k 16..31
  const s16x8 pA0 = __builtin_bit_cast(s16x8, pa0);
  const s16x8 pA1 = __builtin_bit_cast(s16x8, pa1);
  o = MFMA3216(pA0, va0, o);
  o = MFMA3216(pA1, va1, o);
  o_l = MFMA3216(pA0, ones8, o_l);
  o_l = MFMA3216(pA1, ones8, o_l);
}

// Compute one 64-token tile from LDS buffer BUF (static index).
#define ATILE(BUF)                                                       \
  {                                                                      \
    const ushort* kb = &KVs[BUF][0];                                     \
    const ushort* vb = &KVs[BUF][2048];                                  \
    f32x16 S0 = MFMA3216(*(const s16x8*)(kb + lo8), qf0, fz);            \
    S0 = MFMA3216(*(const s16x8*)(kb + 512 + lo8), qf1, S0);             \
    softpv(S0, *(const s16x8*)(vb + lo8), *(const s16x8*)(vb + 512 + lo8), \
           o, o_l);                                                      \
    f32x16 S1 = MFMA3216(*(const s16x8*)(kb + 1024 + lo8), qf0, fz);     \
    S1 = MFMA3216(*(const s16x8*)(kb + 1536 + lo8), qf1, S1);            \
    softpv(S1, *(const s16x8*)(vb + 1024 + lo8),                         \
           *(const s16x8*)(vb + 1536 + lo8), o, o_l);                    \
  }

__global__ __launch_bounds__(256, 4) void attn_split(
    const ushort* __restrict__ QG, const ushort* __restrict__ KG,
    const ushort* __restrict__ VtG, ushort* __restrict__ OF0,
    ushort* __restrict__ OFb, float* __restrict__ LF) {
  __shared__ __align__(64) ushort KVs[2][4096];  // per buf: K 2048, V 2048
  const int id = blockIdx.x;
  const int bh = (id & 7) * 2 + ((id >> 3) & 1);  // XCD-affine heads
  const int q0 = ((id >> 4) & 31) * 128;
  const int sp = id >> 9;   // split index 0..1
  const int kt0 = sp * 32;  // 32 k-tiles (64 tok each) per split
  const int t = threadIdx.x;
  const int wid = t >> 6, lane = t & 63;
  const int l5 = lane & 31, hi = lane >> 5;
  const int lo8 = lane * 8;
  const ushort* qp = QG + (size_t)bh * 4096 * 32;
  const int qw = q0 + 32 * wid;
  // Q fragments (held in regs): B[dk = h*16 + hi*8 + e][q = l5]
  const ushort* qrow = qp + (size_t)(qw + l5) * 32 + hi * 8;
  const s16x8 qf0 = *(const s16x8*)(qrow);
  const s16x8 qf1 = *(const s16x8*)(qrow + 16);
  // Staging: wave wid stages the 1KB chunk at kdst of both K and V.
  const int kdst = wid * 512;
  const ushort* kpre = KG + (size_t)bh * 131072 + (size_t)kt0 * 2048 + kdst + lo8;
  const ushort* vpre = VtG + (size_t)bh * 131072 + (size_t)kt0 * 2048 + kdst + lo8;
  stage16(kpre, &KVs[0][kdst], lane);
  stage16(vpre, &KVs[0][2048 + kdst], lane);
  kpre += 2048;
  vpre += 2048;
  __syncthreads();
  f32x16 o = {};
  f32x16 o_l = {};
  const f32x16 fz = {};  // loop-invariant zero C operand for QK MFMAs
  for (int p = 0; p < 16; ++p) {
    // Stage tile 2p+1 into buf1; compute tile 2p from buf0.
    stage16(kpre, &KVs[1][kdst], lane);
    stage16(vpre, &KVs[1][2048 + kdst], lane);
    kpre += 2048;
    vpre += 2048;
    ATILE(0)
    __syncthreads();
    // Stage tile 2p+2 into buf0 (if any); compute tile 2p+1 from buf1.
    if (p < 15) {
      stage16(kpre, &KVs[0][kdst], lane);
      stage16(vpre, &KVs[0][2048 + kdst], lane);
      kpre += 2048;
      vpre += 2048;
    }
    ATILE(1)
    __syncthreads();
  }
  // Store un-normalized bf16 partial O + f32 partial l.
  ushort* OFs = (sp == 0) ? OF0 : OFb;
  float* LFs = LF + (size_t)sp * 65536;
#pragma unroll
  for (int r = 0; r < 16; ++r) {
    int q = qw + (r & 3) + 8 * (r >> 2) + 4 * hi;
    OFs[((size_t)bh * 4096 + q) * 32 + l5] = bfr(o[r]);
  }
  // o_l: C[row=q][col=d], l[q] replicated across d. Lanes l5<16 store row
  // r=l5 of their hi-half.
  float lval = o_l[0];
#pragma unroll
  for (int r = 1; r < 16; ++r) lval = (l5 == r) ? o_l[r] : lval;
  if (l5 < 16)
    LFs[(size_t)bh * 4096 + qw + (l5 & 3) + 8 * (l5 >> 2) + 4 * hi] = lval;
}

// ---------------------------------------------------------------------------
// Out-proj with fused 2-way split-combine + normalization in the staging.
// W staged via global_load_lds from fragment-linear woT (linear LDS);
// 64-token tiles -> grid (128,4) = 2 blocks/CU.
// ---------------------------------------------------------------------------
__global__ __launch_bounds__(256) void proj_split(
    const ushort* __restrict__ OF0, const ushort* __restrict__ OFb,
    const float* __restrict__ LF, const ushort* __restrict__ woT,
    const float* __restrict__ bo, float* __restrict__ out) {
  __shared__ __align__(64) ushort WL[2048];
  __shared__ __align__(16) ushort Xl[64][40];
  const int t0 = blockIdx.x * 64;
  const int c0 = blockIdx.y * 64;
  const int t = threadIdx.x;
  const int wid = t >> 6, lane = t & 63;
  const int wy = wid >> 1, wx = wid & 1;
  const int quad = lane >> 4, l16 = lane & 15;
  const int lo8 = lane * 8;
  f32x4 acc[2][2] = {};
  const int c8 = (t & 7) * 4;  // dd column (4 ushorts)
  const ushort* wsrc = woT + (size_t)blockIdx.y * 16384 + wid * 512 + lo8;
  for (int k0 = 0; k0 < 256; k0 += 32) {
    __syncthreads();
    stage16(wsrc + (k0 >> 5) * 2048, &WL[wid * 512], lane);
    const int hh = k0 >> 5;
#pragma unroll
    for (int p = 0; p < 2; ++p) {
      int row = 32 * p + (t >> 3);
      int tok = t0 + row, bb = tok >> 12, tokn = tok & 4095;
      size_t ro = (size_t)(bb * 8 + hh) * 4096 + tokn;
      size_t oi = ro * 32 + c8;
      uint2 a0 = *(const uint2*)(OF0 + oi);
      uint2 a1 = *(const uint2*)(OFb + oi);
      float l = LF[ro] + LF[65536 + ro];
      float inv = RCPF(l);
      f32x4 s;
      s[0] = bflo(a0.x) + bflo(a1.x);
      s[1] = bfhi(a0.x) + bfhi(a1.x);
      s[2] = bflo(a0.y) + bflo(a1.y);
      s[3] = bfhi(a0.y) + bfhi(a1.y);
      s *= inv;
      u32x2 pk = {pkrne(s[0], s[1]), pkrne(s[2], s[3])};
      *(u32x2*)&Xl[row][c8] = pk;
    }
    __syncthreads();
    s16x8 wf[2], xf[2];
#pragma unroll
    for (int i = 0; i < 2; ++i)
      wf[i] = *(const s16x8*)&WL[(2 * wy + i) * 512 + lo8];
#pragma unroll
    for (int j = 0; j < 2; ++j)
      xf[j] = *(const s16x8*)&Xl[32 * wx + 16 * j + l16][quad * 8];
#pragma unroll
    for (int i = 0; i < 2; ++i)
#pragma unroll
      for (int j = 0; j < 2; ++j) acc[i][j] = MFMA32(wf[i], xf[j], acc[i][j]);
  }
#pragma unroll
  for (int i = 0; i < 2; ++i) {
    int cb = c0 + 32 * wy + 16 * i + 4 * quad;
    float4 b4 = *(const float4*)(bo + cb);
    float bb[4] = {b4.x, b4.y, b4.z, b4.w};
#pragma unroll
    for (int j = 0; j < 2; ++j) {
      int tok = t0 + 32 * wx + 16 * j + l16;
      int b = tok >> 12, tokn = tok & 4095;
#pragma unroll
      for (int r = 0; r < 4; ++r)
        out[((size_t)(b * 256 + cb + r)) * 4096 + tokn] = acc[i][j][r] + bb[r];
    }
  }
}

extern "C" void kernel_launch(void* const* d_in, const int* in_sizes, int n_in,
                              void* d_out, int out_size, void* d_ws, size_t ws_size,
                              hipStream_t stream) {
  (void)in_sizes; (void)n_in; (void)out_size; (void)ws_size;
  const float* x = (const float*)d_in[0];
  const float* wq = (const float*)d_in[1];
  const float* bq = (const float*)d_in[2];
  const float* wo = (const float*)d_in[3];
  const float* bo = (const float*)d_in[4];
  float* out = (float*)d_out;
  ushort* ws = (ushort*)d_ws;
  // ws layout:
  ushort* xbf = ws;                    // [8192][256] frag-linear (dead after qkv)
  ushort* OF0 = ws;                    // split0 partial O overlays dead xbf
  ushort* QG  = ws + 2097152;          // [2][8][4096][32]
  ushort* KG  = ws + 4194304;          // fragment-linear tiles
  ushort* VtG = ws + 6291456;          // fragment-linear tiles
  ushort* wT  = ws + 8388608;          // [768][256] frag-linear
  ushort* woT = ws + 8585216;          // [256][256] frag-linear
  ushort* OFb = ws + 8650752;          // split1 partial O: 2,097,152 ushorts
  float* LF = (float*)(ws + 12845056); // [2][16][4096] f32
  prep_kernel<<<576, 256, 0, stream>>>(x, wq, wo, xbf, wT, woT);
  qkv_kernel<<<dim3(64, 12), 256, 0, stream>>>(xbf, wT, bq, QG, KG, VtG);
  attn_split<<<1024, 256, 0, stream>>>(QG, KG, VtG, OF0, OFb, LF);
  proj_split<<<dim3(128, 4), 256, 0, stream>>>(OF0, OFb, LF, woT, bo, out);
}